// Round 23
// baseline (190.756 us; speedup 1.0000x reference)
//
#include <hip/hip_runtime.h>
#include <hip/hip_bf16.h>
#include <stdint.h>

typedef __attribute__((ext_vector_type(8))) short s8v;
typedef __attribute__((ext_vector_type(4))) float f4v;

#define T_TOT 8
#define NSP 32768   // T*H*W
#define K_TOT 1024
#define M_TOT 1024

__device__ __forceinline__ unsigned short f2bf(float f) {
  unsigned int u = __float_as_uint(f);
  u += 0x7FFF + ((u >> 16) & 1);   // round-to-nearest-even
  return (unsigned short)(u >> 16);
}

// ---------------------------------------------------------------------------
// Kernel 1 (round-15 verbatim, ~38us): depthwise 3x3x3 -> Yn[c][n].
// bx==4 blocks cast the pointwise weight (fold).
// ---------------------------------------------------------------------------
__global__ __launch_bounds__(256) void dw_kernel(const float* __restrict__ X,
                                                 const float* __restrict__ DW,
                                                 unsigned short* __restrict__ Yn,
                                                 const float* __restrict__ Wf,
                                                 unsigned short* __restrict__ Wb) {
  if (blockIdx.x == 4) {
    const int i = (blockIdx.y * 256 + threadIdx.x) * 4;
    float4 v = *(const float4*)&Wf[i];
    ushort4 o;
    o.x = f2bf(v.x); o.y = f2bf(v.y); o.z = f2bf(v.z); o.w = f2bf(v.w);
    *(ushort4*)&Wb[i] = o;
    return;
  }

  __shared__ float xin[8 * 18 * 64];         // 36 KB  [t][hr][w]
  const int tid = threadIdx.x;
  const int hb  = blockIdx.x;                // 0..3
  const int c   = blockIdx.y;                // 0..1023
  const int h0  = hb * 16;

  float kw[27];
#pragma unroll
  for (int j = 0; j < 27; ++j) kw[j] = DW[j];

  const float* Xc = X + (size_t)c * NSP;

#pragma unroll
  for (int i = 0; i < 9; ++i) {
    const int f  = tid + i * 256;
    const int r  = f >> 4;
    const int wq = (f & 15) * 4;
    const int t  = r / 18;
    const int hr = r - t * 18;
    const int hg = h0 - 1 + hr;
    const int hc = min(max(hg, 0), 63);
    float4 v = *(const float4*)(Xc + (t * 64 + hc) * 64 + wq);
    if (hg != hc) v = (float4){0.f, 0.f, 0.f, 0.f};
    *(float4*)&xin[r * 64 + wq] = v;
  }
  __syncthreads();

  const int w  = tid & 63;
  const int hq = tid >> 6;
  const int wl = (w == 0)  ? w : w - 1;
  const int wr = (w == 63) ? w : w + 1;
  const float* bC = &xin[(hq * 4) * 64 + w];
  const float* bL = &xin[(hq * 4) * 64 + wl];
  const float* bR = &xin[(hq * 4) * 64 + wr];
  unsigned short* Yb = Yn + (size_t)c * NSP + (h0 + hq * 4) * 64 + w;

  float a0[4], a1[4], a2[4];
#pragma unroll
  for (int j = 0; j < 4; ++j) { a0[j] = 0.f; a1[j] = 0.f; a2[j] = 0.f; }

#pragma unroll
  for (int tp = 0; tp < 8; ++tp) {
    float v[6][3];
#pragma unroll
    for (int rr = 0; rr < 6; ++rr) {
      const int off = (tp * 18 + rr) * 64;
      float xc = bC[off];
      float xl = bL[off];
      float xr = bR[off];
      if (w == 0)  xl = 0.f;
      if (w == 63) xr = 0.f;
      v[rr][0] = xl; v[rr][1] = xc; v[rr][2] = xr;
    }
#pragma unroll
    for (int j = 0; j < 4; ++j)
#pragma unroll
      for (int kh = 0; kh < 3; ++kh)
#pragma unroll
        for (int kd = 0; kd < 3; ++kd) {
          const float xv = v[j + kh][kd];
          if (tp >= 1) a0[j] += kw[(2 * 3 + kh) * 3 + kd] * xv;
          a1[j] += kw[(1 * 3 + kh) * 3 + kd] * xv;
          if (tp <= 6) a2[j] += kw[(0 * 3 + kh) * 3 + kd] * xv;
        }
    if (tp >= 1) {
      unsigned short* yp = Yb + (size_t)(tp - 1) * 4096;
#pragma unroll
      for (int j = 0; j < 4; ++j) yp[j * 64] = f2bf(a0[j]);
    }
#pragma unroll
    for (int j = 0; j < 4; ++j) { a0[j] = a1[j]; a1[j] = a2[j]; a2[j] = 0.f; }
  }
  {
    unsigned short* yp = Yb + (size_t)7 * 4096;
#pragma unroll
    for (int j = 0; j < 4; ++j) yp[j * 64] = f2bf(a0[j]);
  }
}

// ---------------------------------------------------------------------------
// Kernel 1b (round-4 verbatim, ~21us): transpose Yn[c][n] -> Yt[n][c].
// ---------------------------------------------------------------------------
__global__ __launch_bounds__(256) void tr_kernel(const unsigned short* __restrict__ Yn,
                                                 unsigned short* __restrict__ Yt) {
  __shared__ unsigned short tb[64][68];
  const int tid = threadIdx.x;
  const int n0  = blockIdx.x * 64;
  const int c0  = blockIdx.y * 64;

#pragma unroll
  for (int i = 0; i < 2; ++i) {
    const int cl = (tid >> 3) + i * 32;
    const int n8 = (tid & 7) * 8;
    const uint4 v = *(const uint4*)(Yn + (size_t)(c0 + cl) * NSP + n0 + n8);
    uint2 lo; lo.x = v.x; lo.y = v.y;
    uint2 hi; hi.x = v.z; hi.y = v.w;
    *(uint2*)&tb[cl][n8]     = lo;
    *(uint2*)&tb[cl][n8 + 4] = hi;
  }
  __syncthreads();

  const int nl = tid >> 2;
  const int cq = tid & 3;
#pragma unroll
  for (int i = 0; i < 2; ++i) {
    const int c8 = cq * 8 + i * 32;
    unsigned int p[4];
#pragma unroll
    for (int j = 0; j < 4; ++j) {
      const unsigned int a = tb[c8 + 2 * j][nl];
      const unsigned int b = tb[c8 + 2 * j + 1][nl];
      p[j] = a | (b << 16);
    }
    uint4 o; o.x = p[0]; o.y = p[1]; o.z = p[2]; o.w = p[3];
    *(uint4*)(Yt + (size_t)(n0 + nl) * 1024 + c0 + c8) = o;
  }
}

// ---------------------------------------------------------------------------
// Kernel 3 (v13, wave-parity skew): C = A[M][K]*Yt[N][K]^T.
// Base = proven v6 (81.5us): BM=BN=256, BK=64, 512 thr, wave-tile 128x64,
// acc[8][4], LDS 128KB, both-sides XOR swizzle (0 conflicts).
// Schedule change ONLY: per K-tile, stage BOTH kk-halves of t+1 up front
// (8 loads, >=2900cy cover), then ODD waves compute kk1->kk0 while EVEN
// waves compute kk0->kk1 with NO mid-tile barrier (legal: both halves of
// tile t landed before the tile-entry barrier).  One vmcnt(0)+barrier per
// tile (16 barriers, was 32).  Mechanism: at any instant ~half the waves
// feed the LDS port while half feed the matrix pipe -> de-serializes the
// measured 31us port time vs 33us MFMA time (r22 arithmetic).
// ---------------------------------------------------------------------------
__device__ __forceinline__ void gload_lds16(const void* g, void* lds) {
  __builtin_amdgcn_global_load_lds(
      (const __attribute__((address_space(1))) void*)(uintptr_t)g,
      (__attribute__((address_space(3))) void*)(uintptr_t)lds, 16, 0, 0);
}

__global__ __launch_bounds__(512, 2) void gemm8_kernel(const unsigned short* __restrict__ A,
                                                       const unsigned short* __restrict__ B,
                                                       float* __restrict__ C) {
  __shared__ char smem[131072];              // 2 x {A0,A1,B0,B1} x 16KB
  const int tid  = threadIdx.x;
  const int lane = tid & 63;
  const int wid  = tid >> 6;
  const int wm   = wid >> 2, wn = wid & 3;   // 2 x 4 wave grid

  // bijective XCD remap: 512 wgs, 64 per XCD; bm fastest.
  const int wg = (int)blockIdx.x;
  const int lg = (wg & 7) * 64 + (wg >> 3);
  const int bm = lg & 3;                     // 0..3   (M/256)
  const int bn = lg >> 2;                    // 0..127 (N/256)

  f4v acc[8][4];
#pragma unroll
  for (int i = 0; i < 8; ++i)
#pragma unroll
    for (int j = 0; j < 4; ++j) acc[i][j] = (f4v){0.f, 0.f, 0.f, 0.f};

  const int r  = tid >> 2;                                   // 0..127
  const int kb = (((tid & 3) ^ ((tid >> 3) & 3)) * 8);       // pre-swizzled k
  const unsigned short* ga = A + (size_t)(bm * 256 + r) * K_TOT + kb;
  const unsigned short* gb = B + (size_t)(bn * 256 + r) * K_TOT + kb;
  const int stg = wid * 1024;

#define STAGE_KK(nb, tt, kk)                                                  \
  do {                                                                        \
    const int ko = (tt) * 64 + (kk) * 32;                                     \
    char* ab = smem + (nb) + (kk) * 16384 + stg;                              \
    char* bb = smem + (nb) + 32768 + (kk) * 16384 + stg;                      \
    gload_lds16(ga + ko,                 ab);                                 \
    gload_lds16(ga + 128 * K_TOT + ko,   ab + 8192);                          \
    gload_lds16(gb + ko,                 bb);                                 \
    gload_lds16(gb + 128 * K_TOT + ko,   bb + 8192);                          \
  } while (0)

  const int cph  = ((lane >> 4) ^ ((lane >> 1) & 3)) * 8;    // swizzled col
  const int arow = wm * 128 + (lane & 15);
  const int brow = wn * 64  + (lane & 15);

#define PHASE(cu, kk)                                                         \
  do {                                                                        \
    const unsigned short* Ac = (const unsigned short*)(smem + (cu));          \
    const unsigned short* Bc = (const unsigned short*)(smem + (cu) + 32768);  \
    s8v av[8], bv[4];                                                         \
    _Pragma("unroll")                                                         \
    for (int nf = 0; nf < 4; ++nf)                                            \
      bv[nf] = *(const s8v*)&Bc[(kk) * 8192 + (brow + nf * 16) * 32 + cph];   \
    _Pragma("unroll")                                                         \
    for (int mf = 0; mf < 8; ++mf)                                            \
      av[mf] = *(const s8v*)&Ac[(kk) * 8192 + (arow + mf * 16) * 32 + cph];   \
    __builtin_amdgcn_s_setprio(1);                                            \
    _Pragma("unroll")                                                         \
    for (int mf = 0; mf < 8; ++mf)                                            \
      _Pragma("unroll")                                                       \
      for (int nf = 0; nf < 4; ++nf)                                          \
        acc[mf][nf] = __builtin_amdgcn_mfma_f32_16x16x32_bf16(                \
            av[mf], bv[nf], acc[mf][nf], 0, 0, 0);                            \
    __builtin_amdgcn_s_setprio(0);                                            \
  } while (0)

  // prologue: tile 0 both halves (8 loads), full wait
  STAGE_KK(0, 0, 0);
  STAGE_KK(0, 0, 1);
  asm volatile("s_waitcnt vmcnt(0)" ::: "memory");
  __builtin_amdgcn_s_barrier();

  for (int t = 0; t < 15; ++t) {
    const int cu = (t & 1) << 16;
    const int nx = cu ^ 65536;
    // stage ALL of tile t+1 first (dest buffer freed by the entry barrier)
    STAGE_KK(nx, t + 1, 0);
    STAGE_KK(nx, t + 1, 1);
    // wave-parity skew: half the waves read while the other half MFMA
    if (wid & 1) {
      PHASE(cu, 1);
      PHASE(cu, 0);
    } else {
      PHASE(cu, 0);
      PHASE(cu, 1);
    }
    asm volatile("s_waitcnt vmcnt(0)" ::: "memory");  // t+1 landed (~2900cy cover)
    __builtin_amdgcn_s_barrier();
  }
  // tail: tile 15 (buffer 1), nothing to stage
  if (wid & 1) {
    PHASE(65536, 1);
    PHASE(65536, 0);
  } else {
    PHASE(65536, 0);
    PHASE(65536, 1);
  }

#undef PHASE
#undef STAGE_KK

  const int rowq = (lane >> 4) * 4;
  const int colq = lane & 15;
#pragma unroll
  for (int mf = 0; mf < 8; ++mf) {
    const int row0 = bm * 256 + wm * 128 + mf * 16 + rowq;
#pragma unroll
    for (int nf = 0; nf < 4; ++nf) {
      const int col = bn * 256 + wn * 64 + nf * 16 + colq;
      float* cp = C + (size_t)row0 * NSP + col;
#pragma unroll
      for (int j = 0; j < 4; ++j) cp[(size_t)j * NSP] = acc[mf][nf][j];
    }
  }
}

// ---------------------------------------------------------------------------
// Fallback GEMM (round-3 verbatim): consumes Yn[k][n] directly.
// ---------------------------------------------------------------------------
__global__ __launch_bounds__(256) void gemm_nmajor_kernel(const unsigned short* __restrict__ A,
                                                          const unsigned short* __restrict__ B,
                                                          float* __restrict__ C) {
  __shared__ unsigned short As[128][32];
  __shared__ unsigned short Bs[128][40];
  const int tid  = threadIdx.x;
  const int lane = tid & 63;
  const int wv   = tid >> 6;
  const int wr   = wv >> 1, wc = wv & 1;
  const int bn   = blockIdx.x, bm = blockIdx.y;
  const int n0   = bn * 128;

  f4v acc[4][4];
#pragma unroll
  for (int i = 0; i < 4; ++i)
#pragma unroll
    for (int j = 0; j < 4; ++j) acc[i][j] = (f4v){0.f, 0.f, 0.f, 0.f};

  const int r  = tid >> 2;
  const int kb = (tid & 3) * 8;
  const unsigned short* ga0 = A + (size_t)(bm * 128 + r) * K_TOT + kb;
  char* ldsA = (char*)(&As[0][0]) + wv * 1024;
  const int nq4 = (tid >> 3) * 4;
  const int kq4 = (tid & 7) * 4;

  for (int kt = 0; kt < K_TOT; kt += 32) {
    __syncthreads();
    gload_lds16(ga0 + kt,               ldsA);
    gload_lds16(ga0 + 64 * K_TOT + kt,  ldsA + 4096);

    const unsigned short* gB = B + (size_t)(kt + kq4) * NSP + n0 + nq4;
    uint2 L0 = *(const uint2*)(gB);
    uint2 L1 = *(const uint2*)(gB + NSP);
    uint2 L2 = *(const uint2*)(gB + 2 * NSP);
    uint2 L3 = *(const uint2*)(gB + 3 * NSP);
    uint2 W0, W1, W2, W3;
    W0.x = (L0.x & 0xFFFFu) | (L1.x << 16);
    W0.y = (L2.x & 0xFFFFu) | (L3.x << 16);
    W1.x = (L0.x >> 16) | (L1.x & 0xFFFF0000u);
    W1.y = (L2.x >> 16) | (L3.x & 0xFFFF0000u);
    W2.x = (L0.y & 0xFFFFu) | (L1.y << 16);
    W2.y = (L2.y & 0xFFFFu) | (L3.y << 16);
    W3.x = (L0.y >> 16) | (L1.y & 0xFFFF0000u);
    W3.y = (L2.y >> 16) | (L3.y & 0xFFFF0000u);
    *(uint2*)&Bs[nq4 + 0][kq4] = W0;
    *(uint2*)&Bs[nq4 + 1][kq4] = W1;
    *(uint2*)&Bs[nq4 + 2][kq4] = W2;
    *(uint2*)&Bs[nq4 + 3][kq4] = W3;
    __syncthreads();

    s8v a[4], b[4];
#pragma unroll
    for (int mf = 0; mf < 4; ++mf)
      a[mf] = *(const s8v*)&As[wr * 64 + mf * 16 + (lane & 15)][(lane >> 4) * 8];
#pragma unroll
    for (int nf = 0; nf < 4; ++nf)
      b[nf] = *(const s8v*)&Bs[wc * 64 + nf * 16 + (lane & 15)][(lane >> 4) * 8];
#pragma unroll
    for (int mf = 0; mf < 4; ++mf)
#pragma unroll
      for (int nf = 0; nf < 4; ++nf)
        acc[mf][nf] = __builtin_amdgcn_mfma_f32_16x16x32_bf16(a[mf], b[nf], acc[mf][nf], 0, 0, 0);
  }

  const int rowq = (lane >> 4) * 4;
  const int colq = lane & 15;
#pragma unroll
  for (int mf = 0; mf < 4; ++mf) {
    const int row0 = bm * 128 + wr * 64 + mf * 16 + rowq;
#pragma unroll
    for (int nf = 0; nf < 4; ++nf) {
      const int col = n0 + wc * 64 + nf * 16 + colq;
      float* cp = C + (size_t)row0 * NSP + col;
#pragma unroll
      for (int j = 0; j < 4; ++j) cp[(size_t)j * NSP] = acc[mf][nf][j];
    }
  }
}

// ---------------------------------------------------------------------------
extern "C" void kernel_launch(void* const* d_in, const int* in_sizes, int n_in,
                              void* d_out, int out_size, void* d_ws, size_t ws_size,
                              hipStream_t stream) {
  const float* feat = (const float*)d_in[0];
  const float* dw   = (const float*)d_in[1];
  const float* pw   = (const float*)d_in[2];
  float* out = (float*)d_out;

  const size_t YBYTES = (size_t)K_TOT * NSP * 2;   // 64 MiB
  const size_t WBYTES = (size_t)M_TOT * K_TOT * 2; // 2 MiB

  if (ws_size >= 2 * YBYTES + WBYTES) {
    // main path (130 MiB, proven available): Yt@0, Yn@64MiB, Wb@128MiB
    unsigned short* Yt = (unsigned short*)d_ws;
    unsigned short* Yn = (unsigned short*)((char*)d_ws + YBYTES);
    unsigned short* Wb = (unsigned short*)((char*)d_ws + 2 * YBYTES);
    dw_kernel<<<dim3(5, 1024), dim3(256), 0, stream>>>(feat, dw, Yn, pw, Wb);
    tr_kernel<<<dim3(512, 16), dim3(256), 0, stream>>>(Yn, Yt);
    gemm8_kernel<<<dim3(512), dim3(512), 0, stream>>>(Wb, Yt, out);
  } else {
    // fallback (66 MiB, proven round-3 path): Yn@0, Wb@64MiB
    unsigned short* Yn = (unsigned short*)d_ws;
    unsigned short* Wb = Yn + (size_t)K_TOT * NSP;
    dw_kernel<<<dim3(5, 1024), dim3(256), 0, stream>>>(feat, dw, Yn, pw, Wb);
    gemm_nmajor_kernel<<<dim3(256, 8), dim3(256), 0, stream>>>(Wb, Yn, out);
  }
}

// Round 24
// 149.639 us; speedup vs baseline: 1.2748x; 1.2748x over previous
//
#include <hip/hip_runtime.h>
#include <hip/hip_bf16.h>
#include <stdint.h>

typedef __attribute__((ext_vector_type(8))) short s8v;
typedef __attribute__((ext_vector_type(4))) float f4v;

#define T_TOT 8
#define NSP 32768   // T*H*W
#define K_TOT 1024
#define M_TOT 1024

__device__ __forceinline__ unsigned short f2bf(float f) {
  unsigned int u = __float_as_uint(f);
  u += 0x7FFF + ((u >> 16) & 1);   // round-to-nearest-even
  return (unsigned short)(u >> 16);
}

// ---------------------------------------------------------------------------
// Kernel 1 (round-15 verbatim, ~38us): depthwise 3x3x3 -> Yn[c][n].
// bx==4 blocks cast the pointwise weight (fold).
// ---------------------------------------------------------------------------
__global__ __launch_bounds__(256) void dw_kernel(const float* __restrict__ X,
                                                 const float* __restrict__ DW,
                                                 unsigned short* __restrict__ Yn,
                                                 const float* __restrict__ Wf,
                                                 unsigned short* __restrict__ Wb) {
  if (blockIdx.x == 4) {
    const int i = (blockIdx.y * 256 + threadIdx.x) * 4;
    float4 v = *(const float4*)&Wf[i];
    ushort4 o;
    o.x = f2bf(v.x); o.y = f2bf(v.y); o.z = f2bf(v.z); o.w = f2bf(v.w);
    *(ushort4*)&Wb[i] = o;
    return;
  }

  __shared__ float xin[8 * 18 * 64];         // 36 KB  [t][hr][w]
  const int tid = threadIdx.x;
  const int hb  = blockIdx.x;                // 0..3
  const int c   = blockIdx.y;                // 0..1023
  const int h0  = hb * 16;

  float kw[27];
#pragma unroll
  for (int j = 0; j < 27; ++j) kw[j] = DW[j];

  const float* Xc = X + (size_t)c * NSP;

#pragma unroll
  for (int i = 0; i < 9; ++i) {
    const int f  = tid + i * 256;
    const int r  = f >> 4;
    const int wq = (f & 15) * 4;
    const int t  = r / 18;
    const int hr = r - t * 18;
    const int hg = h0 - 1 + hr;
    const int hc = min(max(hg, 0), 63);
    float4 v = *(const float4*)(Xc + (t * 64 + hc) * 64 + wq);
    if (hg != hc) v = (float4){0.f, 0.f, 0.f, 0.f};
    *(float4*)&xin[r * 64 + wq] = v;
  }
  __syncthreads();

  const int w  = tid & 63;
  const int hq = tid >> 6;
  const int wl = (w == 0)  ? w : w - 1;
  const int wr = (w == 63) ? w : w + 1;
  const float* bC = &xin[(hq * 4) * 64 + w];
  const float* bL = &xin[(hq * 4) * 64 + wl];
  const float* bR = &xin[(hq * 4) * 64 + wr];
  unsigned short* Yb = Yn + (size_t)c * NSP + (h0 + hq * 4) * 64 + w;

  float a0[4], a1[4], a2[4];
#pragma unroll
  for (int j = 0; j < 4; ++j) { a0[j] = 0.f; a1[j] = 0.f; a2[j] = 0.f; }

#pragma unroll
  for (int tp = 0; tp < 8; ++tp) {
    float v[6][3];
#pragma unroll
    for (int rr = 0; rr < 6; ++rr) {
      const int off = (tp * 18 + rr) * 64;
      float xc = bC[off];
      float xl = bL[off];
      float xr = bR[off];
      if (w == 0)  xl = 0.f;
      if (w == 63) xr = 0.f;
      v[rr][0] = xl; v[rr][1] = xc; v[rr][2] = xr;
    }
#pragma unroll
    for (int j = 0; j < 4; ++j)
#pragma unroll
      for (int kh = 0; kh < 3; ++kh)
#pragma unroll
        for (int kd = 0; kd < 3; ++kd) {
          const float xv = v[j + kh][kd];
          if (tp >= 1) a0[j] += kw[(2 * 3 + kh) * 3 + kd] * xv;
          a1[j] += kw[(1 * 3 + kh) * 3 + kd] * xv;
          if (tp <= 6) a2[j] += kw[(0 * 3 + kh) * 3 + kd] * xv;
        }
    if (tp >= 1) {
      unsigned short* yp = Yb + (size_t)(tp - 1) * 4096;
#pragma unroll
      for (int j = 0; j < 4; ++j) yp[j * 64] = f2bf(a0[j]);
    }
#pragma unroll
    for (int j = 0; j < 4; ++j) { a0[j] = a1[j]; a1[j] = a2[j]; a2[j] = 0.f; }
  }
  {
    unsigned short* yp = Yb + (size_t)7 * 4096;
#pragma unroll
    for (int j = 0; j < 4; ++j) yp[j * 64] = f2bf(a0[j]);
  }
}

// ---------------------------------------------------------------------------
// Kernel 1b (round-4 verbatim, ~21us): transpose Yn[c][n] -> Yt[n][c].
// ---------------------------------------------------------------------------
__global__ __launch_bounds__(256) void tr_kernel(const unsigned short* __restrict__ Yn,
                                                 unsigned short* __restrict__ Yt) {
  __shared__ unsigned short tb[64][68];
  const int tid = threadIdx.x;
  const int n0  = blockIdx.x * 64;
  const int c0  = blockIdx.y * 64;

#pragma unroll
  for (int i = 0; i < 2; ++i) {
    const int cl = (tid >> 3) + i * 32;
    const int n8 = (tid & 7) * 8;
    const uint4 v = *(const uint4*)(Yn + (size_t)(c0 + cl) * NSP + n0 + n8);
    uint2 lo; lo.x = v.x; lo.y = v.y;
    uint2 hi; hi.x = v.z; hi.y = v.w;
    *(uint2*)&tb[cl][n8]     = lo;
    *(uint2*)&tb[cl][n8 + 4] = hi;
  }
  __syncthreads();

  const int nl = tid >> 2;
  const int cq = tid & 3;
#pragma unroll
  for (int i = 0; i < 2; ++i) {
    const int c8 = cq * 8 + i * 32;
    unsigned int p[4];
#pragma unroll
    for (int j = 0; j < 4; ++j) {
      const unsigned int a = tb[c8 + 2 * j][nl];
      const unsigned int b = tb[c8 + 2 * j + 1][nl];
      p[j] = a | (b << 16);
    }
    uint4 o; o.x = p[0]; o.y = p[1]; o.z = p[2]; o.w = p[3];
    *(uint4*)(Yt + (size_t)(n0 + nl) * 1024 + c0 + c8) = o;
  }
}

// ---------------------------------------------------------------------------
// Kernel 3 (round-9 v6 verbatim, measured 78-82us; best of 10 schedule
// variants): C = A[M][K]*Yt[N][K]^T.  BM=BN=256, BK=64, 512 thr (8 waves
// 2Mx4N), wave-tile 128x64, acc[8][4].  LDS 128KB = 2 buf x
// {Akk0,Akk1,Bkk0,Bkk1} x 16KB [256][32], both-sides XOR swizzle
// (0 conflicts).  kk-split phases; every boundary = vmcnt(4)+s_barrier
// (counted; never drains in steady state).
// ---------------------------------------------------------------------------
__device__ __forceinline__ void gload_lds16(const void* g, void* lds) {
  __builtin_amdgcn_global_load_lds(
      (const __attribute__((address_space(1))) void*)(uintptr_t)g,
      (__attribute__((address_space(3))) void*)(uintptr_t)lds, 16, 0, 0);
}

__global__ __launch_bounds__(512, 2) void gemm8_kernel(const unsigned short* __restrict__ A,
                                                       const unsigned short* __restrict__ B,
                                                       float* __restrict__ C) {
  __shared__ char smem[131072];              // 2 x {A0,A1,B0,B1} x 16KB
  const int tid  = threadIdx.x;
  const int lane = tid & 63;
  const int wid  = tid >> 6;
  const int wm   = wid >> 2, wn = wid & 3;   // 2 x 4 wave grid

  // bijective XCD remap: 512 wgs, 64 per XCD; bm fastest.
  const int wg = (int)blockIdx.x;
  const int lg = (wg & 7) * 64 + (wg >> 3);
  const int bm = lg & 3;                     // 0..3   (M/256)
  const int bn = lg >> 2;                    // 0..127 (N/256)

  f4v acc[8][4];
#pragma unroll
  for (int i = 0; i < 8; ++i)
#pragma unroll
    for (int j = 0; j < 4; ++j) acc[i][j] = (f4v){0.f, 0.f, 0.f, 0.f};

  const int r  = tid >> 2;                                   // 0..127
  const int kb = (((tid & 3) ^ ((tid >> 3) & 3)) * 8);       // pre-swizzled k
  const unsigned short* ga = A + (size_t)(bm * 256 + r) * K_TOT + kb;
  const unsigned short* gb = B + (size_t)(bn * 256 + r) * K_TOT + kb;
  const int stg = wid * 1024;

#define STAGE_KK(nb, tt, kk)                                                  \
  do {                                                                        \
    const int ko = (tt) * 64 + (kk) * 32;                                     \
    char* ab = smem + (nb) + (kk) * 16384 + stg;                              \
    char* bb = smem + (nb) + 32768 + (kk) * 16384 + stg;                      \
    gload_lds16(ga + ko,                 ab);                                 \
    gload_lds16(ga + 128 * K_TOT + ko,   ab + 8192);                          \
    gload_lds16(gb + ko,                 bb);                                 \
    gload_lds16(gb + 128 * K_TOT + ko,   bb + 8192);                          \
  } while (0)

  const int cph  = ((lane >> 4) ^ ((lane >> 1) & 3)) * 8;    // swizzled col
  const int arow = wm * 128 + (lane & 15);
  const int brow = wn * 64  + (lane & 15);

#define PHASE(cu, nx, tt, kk, pf)                                             \
  do {                                                                        \
    const unsigned short* Ac = (const unsigned short*)(smem + (cu));          \
    const unsigned short* Bc = (const unsigned short*)(smem + (cu) + 32768);  \
    s8v av[8], bv[4];                                                         \
    _Pragma("unroll")                                                         \
    for (int nf = 0; nf < 4; ++nf)                                            \
      bv[nf] = *(const s8v*)&Bc[(kk) * 8192 + (brow + nf * 16) * 32 + cph];   \
    _Pragma("unroll")                                                         \
    for (int mf = 0; mf < 8; ++mf)                                            \
      av[mf] = *(const s8v*)&Ac[(kk) * 8192 + (arow + mf * 16) * 32 + cph];   \
    if (pf) STAGE_KK(nx, (tt) + 1, kk);                                       \
    __builtin_amdgcn_s_setprio(1);                                            \
    _Pragma("unroll")                                                         \
    for (int mf = 0; mf < 8; ++mf)                                            \
      _Pragma("unroll")                                                       \
      for (int nf = 0; nf < 4; ++nf)                                          \
        acc[mf][nf] = __builtin_amdgcn_mfma_f32_16x16x32_bf16(                \
            av[mf], bv[nf], acc[mf][nf], 0, 0, 0);                            \
    __builtin_amdgcn_s_setprio(0);                                            \
  } while (0)

  // prologue: tile 0 both halves in flight (8 loads)
  STAGE_KK(0, 0, 0);
  STAGE_KK(0, 0, 1);

  for (int t = 0; t < 15; ++t) {
    const int cu = (t & 1) << 16;
    const int nx = cu ^ 65536;
    asm volatile("s_waitcnt vmcnt(4)" ::: "memory");   // t.kk0 landed; t.kk1 may fly
    __builtin_amdgcn_s_barrier();
    PHASE(cu, nx, t, 0, true);                         // issues t+1.kk0
    asm volatile("s_waitcnt vmcnt(4)" ::: "memory");   // t.kk1 landed; t+1.kk0 may fly
    __builtin_amdgcn_s_barrier();
    PHASE(cu, nx, t, 1, true);                         // issues t+1.kk1
  }
  // tail: tile 15 (buffer 1), nothing left to prefetch
  asm volatile("s_waitcnt vmcnt(0)" ::: "memory");
  __builtin_amdgcn_s_barrier();
  PHASE(65536, 0, 15, 0, false);
  PHASE(65536, 0, 15, 1, false);

#undef PHASE
#undef STAGE_KK

  const int rowq = (lane >> 4) * 4;
  const int colq = lane & 15;
#pragma unroll
  for (int mf = 0; mf < 8; ++mf) {
    const int row0 = bm * 256 + wm * 128 + mf * 16 + rowq;
#pragma unroll
    for (int nf = 0; nf < 4; ++nf) {
      const int col = bn * 256 + wn * 64 + nf * 16 + colq;
      float* cp = C + (size_t)row0 * NSP + col;
#pragma unroll
      for (int j = 0; j < 4; ++j) cp[(size_t)j * NSP] = acc[mf][nf][j];
    }
  }
}

// ---------------------------------------------------------------------------
// Fallback GEMM (round-3 verbatim): consumes Yn[k][n] directly.
// ---------------------------------------------------------------------------
__global__ __launch_bounds__(256) void gemm_nmajor_kernel(const unsigned short* __restrict__ A,
                                                          const unsigned short* __restrict__ B,
                                                          float* __restrict__ C) {
  __shared__ unsigned short As[128][32];
  __shared__ unsigned short Bs[128][40];
  const int tid  = threadIdx.x;
  const int lane = tid & 63;
  const int wv   = tid >> 6;
  const int wr   = wv >> 1, wc = wv & 1;
  const int bn   = blockIdx.x, bm = blockIdx.y;
  const int n0   = bn * 128;

  f4v acc[4][4];
#pragma unroll
  for (int i = 0; i < 4; ++i)
#pragma unroll
    for (int j = 0; j < 4; ++j) acc[i][j] = (f4v){0.f, 0.f, 0.f, 0.f};

  const int r  = tid >> 2;
  const int kb = (tid & 3) * 8;
  const unsigned short* ga0 = A + (size_t)(bm * 128 + r) * K_TOT + kb;
  char* ldsA = (char*)(&As[0][0]) + wv * 1024;
  const int nq4 = (tid >> 3) * 4;
  const int kq4 = (tid & 7) * 4;

  for (int kt = 0; kt < K_TOT; kt += 32) {
    __syncthreads();
    gload_lds16(ga0 + kt,               ldsA);
    gload_lds16(ga0 + 64 * K_TOT + kt,  ldsA + 4096);

    const unsigned short* gB = B + (size_t)(kt + kq4) * NSP + n0 + nq4;
    uint2 L0 = *(const uint2*)(gB);
    uint2 L1 = *(const uint2*)(gB + NSP);
    uint2 L2 = *(const uint2*)(gB + 2 * NSP);
    uint2 L3 = *(const uint2*)(gB + 3 * NSP);
    uint2 W0, W1, W2, W3;
    W0.x = (L0.x & 0xFFFFu) | (L1.x << 16);
    W0.y = (L2.x & 0xFFFFu) | (L3.x << 16);
    W1.x = (L0.x >> 16) | (L1.x & 0xFFFF0000u);
    W1.y = (L2.x >> 16) | (L3.x & 0xFFFF0000u);
    W2.x = (L0.y & 0xFFFFu) | (L1.y << 16);
    W2.y = (L2.y & 0xFFFFu) | (L3.y << 16);
    W3.x = (L0.y >> 16) | (L1.y & 0xFFFF0000u);
    W3.y = (L2.y >> 16) | (L3.y & 0xFFFF0000u);
    *(uint2*)&Bs[nq4 + 0][kq4] = W0;
    *(uint2*)&Bs[nq4 + 1][kq4] = W1;
    *(uint2*)&Bs[nq4 + 2][kq4] = W2;
    *(uint2*)&Bs[nq4 + 3][kq4] = W3;
    __syncthreads();

    s8v a[4], b[4];
#pragma unroll
    for (int mf = 0; mf < 4; ++mf)
      a[mf] = *(const s8v*)&As[wr * 64 + mf * 16 + (lane & 15)][(lane >> 4) * 8];
#pragma unroll
    for (int nf = 0; nf < 4; ++nf)
      b[nf] = *(const s8v*)&Bs[wc * 64 + nf * 16 + (lane & 15)][(lane >> 4) * 8];
#pragma unroll
    for (int mf = 0; mf < 4; ++mf)
#pragma unroll
      for (int nf = 0; nf < 4; ++nf)
        acc[mf][nf] = __builtin_amdgcn_mfma_f32_16x16x32_bf16(a[mf], b[nf], acc[mf][nf], 0, 0, 0);
  }

  const int rowq = (lane >> 4) * 4;
  const int colq = lane & 15;
#pragma unroll
  for (int mf = 0; mf < 4; ++mf) {
    const int row0 = bm * 128 + wr * 64 + mf * 16 + rowq;
#pragma unroll
    for (int nf = 0; nf < 4; ++nf) {
      const int col = n0 + wc * 64 + nf * 16 + colq;
      float* cp = C + (size_t)row0 * NSP + col;
#pragma unroll
      for (int j = 0; j < 4; ++j) cp[(size_t)j * NSP] = acc[mf][nf][j];
    }
  }
}

// ---------------------------------------------------------------------------
extern "C" void kernel_launch(void* const* d_in, const int* in_sizes, int n_in,
                              void* d_out, int out_size, void* d_ws, size_t ws_size,
                              hipStream_t stream) {
  const float* feat = (const float*)d_in[0];
  const float* dw   = (const float*)d_in[1];
  const float* pw   = (const float*)d_in[2];
  float* out = (float*)d_out;

  const size_t YBYTES = (size_t)K_TOT * NSP * 2;   // 64 MiB
  const size_t WBYTES = (size_t)M_TOT * K_TOT * 2; // 2 MiB

  if (ws_size >= 2 * YBYTES + WBYTES) {
    // main path (130 MiB, proven available): Yt@0, Yn@64MiB, Wb@128MiB
    unsigned short* Yt = (unsigned short*)d_ws;
    unsigned short* Yn = (unsigned short*)((char*)d_ws + YBYTES);
    unsigned short* Wb = (unsigned short*)((char*)d_ws + 2 * YBYTES);
    dw_kernel<<<dim3(5, 1024), dim3(256), 0, stream>>>(feat, dw, Yn, pw, Wb);
    tr_kernel<<<dim3(512, 16), dim3(256), 0, stream>>>(Yn, Yt);
    gemm8_kernel<<<dim3(512), dim3(512), 0, stream>>>(Wb, Yt, out);
  } else {
    // fallback (66 MiB, proven round-3 path): Yn@0, Wb@64MiB
    unsigned short* Yn = (unsigned short*)d_ws;
    unsigned short* Wb = Yn + (size_t)K_TOT * NSP;
    dw_kernel<<<dim3(5, 1024), dim3(256), 0, stream>>>(feat, dw, Yn, pw, Wb);
    gemm_nmajor_kernel<<<dim3(256, 8), dim3(256), 0, stream>>>(Wb, Yn, out);
  }
}